// Round 2
// baseline (257.246 us; speedup 1.0000x reference)
//
#include <hip/hip_runtime.h>
#include <math.h>

#define AN 120000
#define BN 16
#define GN 32
#define APT 4                          // anchors per thread
#define BLK 256
#define TILE (BLK * APT)               // 1024 anchors per block
#define NBX ((AN + TILE - 1) / TILE)   // 118 blocks along anchors

__device__ __forceinline__ float sl1(float d) {
    float ad = fabsf(d);
    return ad < 1.0f ? 0.5f * d * d : ad - 0.5f;
}

// Stage 1: each thread owns 4 anchors -> each LDS broadcast of a GT box feeds
// 4x13 VALU ops (ILP hides LDS latency inside one wave). Division-free pos
// test: IoU>=0.5  <=>  3*inter >= area_a + area_g.
__global__ __launch_bounds__(256) void loss_main(
    const float* __restrict__ pred_cls,
    const float* __restrict__ pred_bbox,
    const float* __restrict__ pred_ldm,
    const float* __restrict__ anchors,
    const float* __restrict__ gt_boxes,
    const float* __restrict__ gt_ldm,
    float* __restrict__ partial)       // [4][BN][NBX]
{
    __shared__ float4 gtb[GN];
    __shared__ float  sg[GN];
    __shared__ float  gl[GN * 11];     // stride 11 -> conflict-free gather
    __shared__ float  red[4][4];

    const int b   = blockIdx.y;
    const int tid = threadIdx.x;

    if (tid < GN) {
        float4 box = *(const float4*)(gt_boxes + (b * GN + tid) * 4);
        gtb[tid] = box;
        sg[tid]  = (box.z - box.x) * (box.w - box.y);
        const float* lp = gt_ldm + (b * GN + tid) * 10;
        #pragma unroll
        for (int j = 0; j < 10; ++j) gl[tid * 11 + j] = lp[j];
    }
    __syncthreads();

    const int base = blockIdx.x * TILE + tid;

    float4 an4[APT];
    float  sa[APT];
    bool   val[APT];
    bool   pos[APT];

    #pragma unroll
    for (int k = 0; k < APT; ++k) {
        const int a = base + k * BLK;
        val[k] = (a < AN);
        pos[k] = false;
        if (val[k]) {
            an4[k] = *(const float4*)(anchors + (size_t)a * 4);
        } else {
            an4[k] = make_float4(0.f, 0.f, 0.f, 0.f);   // yields inter=0, sa=0 -> never pos
        }
        sa[k] = (an4[k].z - an4[k].x) * (an4[k].w - an4[k].y);
    }

    // Hot loop: one LDS broadcast per g serves 4 anchors.
    #pragma unroll
    for (int g = 0; g < GN; ++g) {
        const float4 gb = gtb[g];
        const float  s3 = sg[g];
        #pragma unroll
        for (int k = 0; k < APT; ++k) {
            float iw = fmaxf(fminf(an4[k].z, gb.z) - fmaxf(an4[k].x, gb.x), 0.f);
            float ih = fmaxf(fminf(an4[k].w, gb.w) - fmaxf(an4[k].y, gb.y), 0.f);
            float inter = iw * ih;
            pos[k] = pos[k] | (3.f * inter >= sa[k] + s3);
        }
    }

    float ce = 0.f, np = 0.f, rl = 0.f, ll = 0.f;

    #pragma unroll
    for (int k = 0; k < APT; ++k) {
        if (!val[k]) continue;
        const int a = base + k * BLK;

        // CE: stable lse = max + log(1 + exp(-|d|)), hardware exp/log.
        float2 pc = *(const float2*)(pred_cls + ((size_t)b * AN + a) * 2);
        float d  = pc.x - pc.y;
        float e  = __expf(-fabsf(d));
        float lse = fmaxf(pc.x, pc.y) + __logf(1.f + e);
        ce += lse - (pos[k] ? pc.y : pc.x);

        // Cold path: ~0.05% of anchors.
        if (pos[k]) {
            float bi = -1.f, bu = 1.f; int bg = 0;
            #pragma unroll
            for (int g = 0; g < GN; ++g) {
                float4 gb = gtb[g];
                float iw = fmaxf(fminf(an4[k].z, gb.z) - fmaxf(an4[k].x, gb.x), 0.f);
                float ih = fmaxf(fminf(an4[k].w, gb.w) - fmaxf(an4[k].y, gb.y), 0.f);
                float inter = iw * ih;
                float uni = sa[k] + sg[g] - inter;
                bool upd = inter * bu > bi * uni;     // strict > keeps first max
                bi = upd ? inter : bi;
                bu = upd ? uni   : bu;
                bg = upd ? g     : bg;
            }
            np += 1.f;
            float4 gb = gtb[bg];
            float aw = an4[k].z - an4[k].x, ah = an4[k].w - an4[k].y;
            float acx = an4[k].x + 0.5f * aw, acy = an4[k].y + 0.5f * ah;
            float gw = gb.z - gb.x, gh = gb.w - gb.y;
            float gcx = gb.x + 0.5f * gw, gcy = gb.y + 0.5f * gh;
            float t0 = (gcx - acx) / aw;
            float t1 = (gcy - acy) / ah;
            float t2 = __logf(gw / aw);
            float t3 = __logf(gh / ah);
            const float4 pb = *(const float4*)(pred_bbox + ((size_t)b * AN + a) * 4);
            rl += sl1(pb.x - t0) + sl1(pb.y - t1) + sl1(pb.z - t2) + sl1(pb.w - t3);
            const float* pl = pred_ldm + ((size_t)b * AN + a) * 10;
            float s = 0.f;
            #pragma unroll
            for (int j = 0; j < 10; ++j) s += sl1(pl[j] - gl[bg * 11 + j]);
            ll += s;
        }
    }

    // Block reduction: wave shuffle then cross-wave via LDS.
    #pragma unroll
    for (int off = 32; off > 0; off >>= 1) {
        ce += __shfl_down(ce, off, 64);
        np += __shfl_down(np, off, 64);
        rl += __shfl_down(rl, off, 64);
        ll += __shfl_down(ll, off, 64);
    }
    const int lane = tid & 63, wid = tid >> 6;
    if (lane == 0) { red[0][wid] = ce; red[1][wid] = np; red[2][wid] = rl; red[3][wid] = ll; }
    __syncthreads();
    if (tid < 4) {
        float s = red[tid][0] + red[tid][1] + red[tid][2] + red[tid][3];
        partial[(size_t)tid * (BN * NBX) + (size_t)b * NBX + blockIdx.x] = s;
    }
}

// Stage 2 (fused finalize): 64 rows of NBX partials; 4 lanes per row.
__global__ __launch_bounds__(256) void reduce_finalize(
    const float* __restrict__ partial, float* __restrict__ out)
{
    __shared__ float rowsum[64];
    const int tid = threadIdx.x;
    const int row = tid >> 2;          // 0..63 = q*16+b
    const int sub = tid & 3;

    float s = 0.f;
    const float* p = partial + (size_t)row * NBX;
    for (int j = sub; j < NBX; j += 4) s += p[j];
    s += __shfl_down(s, 1, 64);
    s += __shfl_down(s, 2, 64);
    if (sub == 0) rowsum[row] = s;
    __syncthreads();

    if (tid == 0) {
        float cls = 0.f, reg = 0.f, ldm = 0.f;
        for (int b = 0; b < BN; ++b) {
            cls += rowsum[0 * BN + b] / (float)AN;
            float npv = rowsum[1 * BN + b];
            float den = fmaxf(npv, 1.f);
            bool has = npv > 0.f;
            reg += has ? rowsum[2 * BN + b] / (den * 4.f)  : 0.f;
            ldm += has ? rowsum[3 * BN + b] / (den * 10.f) : 0.f;
        }
        cls /= (float)BN; reg /= (float)BN; ldm /= (float)BN;
        out[0] = cls + reg + ldm;
        out[1] = cls;
        out[2] = reg;
        out[3] = ldm;
    }
}

extern "C" void kernel_launch(void* const* d_in, const int* in_sizes, int n_in,
                              void* d_out, int out_size, void* d_ws, size_t ws_size,
                              hipStream_t stream) {
    const float* pred_cls  = (const float*)d_in[0];
    const float* pred_bbox = (const float*)d_in[1];
    const float* pred_ldm  = (const float*)d_in[2];
    const float* anchors   = (const float*)d_in[3];
    const float* gt_boxes  = (const float*)d_in[4];
    const float* gt_ldm    = (const float*)d_in[5];
    float* out = (float*)d_out;

    float* partial = (float*)d_ws;     // 4*16*118 floats = 30 KB

    dim3 grid1(NBX, BN);
    loss_main<<<grid1, BLK, 0, stream>>>(pred_cls, pred_bbox, pred_ldm,
                                         anchors, gt_boxes, gt_ldm, partial);
    reduce_finalize<<<1, 256, 0, stream>>>(partial, out);
}